// Round 1
// baseline (7796.259 us; speedup 1.0000x reference)
//
#include <hip/hip_runtime.h>
#include <hip/hip_cooperative_groups.h>
#include <cstdint>
#include <cstddef>

#define SEQ  512
#define BATCH 64
#define DIN  256
#define HDIM 1024

typedef __attribute__((ext_vector_type(8)))  short  short8;
typedef __attribute__((ext_vector_type(4)))  short  short4v;
typedef __attribute__((ext_vector_type(16))) float  float16;
typedef __attribute__((ext_vector_type(4)))  float  float4v;

__device__ __forceinline__ short f2bf(float f) {
    union { float f; uint32_t u; } v; v.f = f;
    uint32_t u = v.u;
    uint32_t r = (u + 0x7fffu + ((u >> 16) & 1u)) >> 16;
    return (short)(r & 0xffffu);
}
__device__ __forceinline__ float bf2f(short s) {
    union { uint32_t u; float f; } v; v.u = ((uint32_t)(uint16_t)s) << 16;
    return v.f;
}

// ---------------------------------------------------------------------------
// prep: W_hh -> bf16 hi/lo planes; zero h double-buffer (buf 0, both planes)
// ---------------------------------------------------------------------------
__global__ void prep_kernel(const float* __restrict__ W_hh,
                            short* __restrict__ w_hi,
                            short* __restrict__ w_lo,
                            short* __restrict__ hbuf) {
    int tid = blockIdx.x * blockDim.x + threadIdx.x;
    int stride = gridDim.x * blockDim.x;
    for (int i = tid; i < HDIM * HDIM; i += stride) {
        float w = W_hh[i];
        short hi = f2bf(w);
        float lo = w - bf2f(hi);
        w_hi[i] = hi;
        w_lo[i] = f2bf(lo);
    }
    // zero buffer 0 (planes 0 and 1): first 2*BATCH*HDIM shorts
    for (int i = tid; i < 2 * BATCH * HDIM; i += stride) hbuf[i] = 0;
}

// ---------------------------------------------------------------------------
// xproj: out[r][j] = sum_i X[r][i] * Win[j][i] + bias[j]
// fp32 tiled GEMM, BM=BN=128, BK=32, 256 threads, 8x8 microtile
// ---------------------------------------------------------------------------
#define XBM 128
#define XBN 128
#define XBK 32

__global__ __launch_bounds__(256) void xproj_kernel(
    const float* __restrict__ X,     // [SEQ*BATCH][DIN]
    const float* __restrict__ Win,   // [HDIM][DIN]
    const float* __restrict__ bias,  // [HDIM]
    float* __restrict__ out)         // [SEQ*BATCH][HDIM]
{
    __shared__ float As[XBK][XBM + 4];
    __shared__ float Bs[XBK][XBN + 4];
    const int bm = blockIdx.x;      // 0..255
    const int bn = blockIdx.y;      // 0..7
    const int r0 = bm * XBM, c0 = bn * XBN;
    const int tid = threadIdx.x;
    const int tx = tid & 15, ty = tid >> 4;

    float acc[8][8];
#pragma unroll
    for (int i = 0; i < 8; i++)
#pragma unroll
        for (int j = 0; j < 8; j++) acc[i][j] = 0.f;

    for (int k0 = 0; k0 < DIN; k0 += XBK) {
#pragma unroll
        for (int r = 0; r < 4; r++) {
            int row = (tid >> 3) + 32 * r;
            int kk  = (tid & 7) * 4;
            float4v v = *(const float4v*)(X + (size_t)(r0 + row) * DIN + k0 + kk);
            As[kk + 0][row] = v[0]; As[kk + 1][row] = v[1];
            As[kk + 2][row] = v[2]; As[kk + 3][row] = v[3];
        }
#pragma unroll
        for (int r = 0; r < 4; r++) {
            int row = (tid >> 3) + 32 * r;
            int kk  = (tid & 7) * 4;
            float4v v = *(const float4v*)(Win + (size_t)(c0 + row) * DIN + k0 + kk);
            Bs[kk + 0][row] = v[0]; Bs[kk + 1][row] = v[1];
            Bs[kk + 2][row] = v[2]; Bs[kk + 3][row] = v[3];
        }
        __syncthreads();
#pragma unroll
        for (int k = 0; k < XBK; k++) {
            float4v a0 = *(const float4v*)&As[k][ty * 8];
            float4v a1 = *(const float4v*)&As[k][ty * 8 + 4];
            float4v b0 = *(const float4v*)&Bs[k][tx * 8];
            float4v b1 = *(const float4v*)&Bs[k][tx * 8 + 4];
            float a[8] = {a0[0],a0[1],a0[2],a0[3],a1[0],a1[1],a1[2],a1[3]};
            float b[8] = {b0[0],b0[1],b0[2],b0[3],b1[0],b1[1],b1[2],b1[3]};
#pragma unroll
            for (int i = 0; i < 8; i++)
#pragma unroll
                for (int j = 0; j < 8; j++) acc[i][j] += a[i] * b[j];
        }
        __syncthreads();
    }

    float4v ba = *(const float4v*)(bias + c0 + tx * 8);
    float4v bb = *(const float4v*)(bias + c0 + tx * 8 + 4);
#pragma unroll
    for (int i = 0; i < 8; i++) {
        size_t row = (size_t)(r0 + ty * 8 + i);
        float4v v0, v1;
#pragma unroll
        for (int j = 0; j < 4; j++) { v0[j] = acc[i][j] + ba[j]; v1[j] = acc[i][4 + j] + bb[j]; }
        *(float4v*)(out + row * HDIM + c0 + tx * 8)     = v0;
        *(float4v*)(out + row * HDIM + c0 + tx * 8 + 4) = v1;
    }
}

// ---------------------------------------------------------------------------
// rnn: persistent cooperative kernel. 32 blocks x 512 threads.
// Block = 32-column H slab. 8 waves = 2 M-tiles(32b) x 4 K-quarters(256k).
// W_hh slab lives in registers as MFMA B-fragments (hi+lo, 128 VGPR).
// Per step: A-frags from global h planes (L2), 48 MFMA, LDS k-reduce,
// fused tanh/blend epilogue, publish h hi/lo to other buffer, grid.sync().
// ---------------------------------------------------------------------------
__global__ __launch_bounds__(512, 2) void rnn_kernel(
    const float* __restrict__ alpha,
    const short* __restrict__ w_hi,
    const short* __restrict__ w_lo,
    short* __restrict__ hbuf,   // [2 buf][2 plane][BATCH][HDIM] shorts
    float* __restrict__ out)    // [SEQ][BATCH][HDIM] fp32, then h_n [BATCH][HDIM]
{
    cooperative_groups::grid_group grid = cooperative_groups::this_grid();
    __shared__ float zbuf[2][4][32][32];   // [mt][kq][m][n]

    const int slab = blockIdx.x;        // 0..31
    const int j0 = slab * 32;
    const int tid = threadIdx.x;
    const int wave = tid >> 6;          // 0..7
    const int lane = tid & 63;
    const int mt = wave >> 2;           // 0..1  -> b0
    const int kq = wave & 3;            // 0..3  -> k0
    const int b0 = mt * 32;
    const int k0 = kq * 256;
    const int n  = lane & 31;           // output column within slab / A row
    const int kg = lane >> 5;           // k-group (8 elems each)

    // --- preload W fragments (persist across all 512 steps) ---
    short8 wfh[16], wfl[16];
#pragma unroll
    for (int kt = 0; kt < 16; kt++) {
        int k = k0 + kt * 16 + kg * 8;
        wfh[kt] = *(const short8*)(w_hi + (size_t)(j0 + n) * HDIM + k);
        wfl[kt] = *(const short8*)(w_lo + (size_t)(j0 + n) * HDIM + k);
    }

    // epilogue thread mapping: b = tid>>3 (0..63), n4 = (tid&7)*4
    const int eb  = tid >> 3;
    const int en4 = (tid & 7) * 4;
    const int emt = eb >> 5, em = eb & 31;
    const int ej  = j0 + en4;

    for (int t = 0; t < SEQ; t++) {
        const int cur = t & 1, nxt = cur ^ 1;
        const short* hhi = hbuf + (size_t)(cur * 2 + 0) * BATCH * HDIM;
        const short* hlo = hbuf + (size_t)(cur * 2 + 1) * BATCH * HDIM;

        // --- MFMA phase: partial z over this wave's k-quarter ---
        float16 acc = (float16)(0.0f);
        const int row = b0 + n;
        const short* phi = hhi + (size_t)row * HDIM + k0 + kg * 8;
        const short* plo = hlo + (size_t)row * HDIM + k0 + kg * 8;
#pragma unroll
        for (int kt = 0; kt < 16; kt++) {
            short8 ahi = *(const short8*)(phi + kt * 16);
            short8 alo = *(const short8*)(plo + kt * 16);
            acc = __builtin_amdgcn_mfma_f32_32x32x16_bf16(ahi, wfh[kt], acc, 0, 0, 0);
            acc = __builtin_amdgcn_mfma_f32_32x32x16_bf16(ahi, wfl[kt], acc, 0, 0, 0);
            acc = __builtin_amdgcn_mfma_f32_32x32x16_bf16(alo, wfh[kt], acc, 0, 0, 0);
        }
        // scatter partials: C/D layout col=lane&31, row=(reg&3)+8*(reg>>2)+4*kg
#pragma unroll
        for (int reg = 0; reg < 16; reg++) {
            int m = (reg & 3) + 8 * (reg >> 2) + 4 * kg;
            zbuf[mt][kq][m][n] = acc[reg];
        }
        __syncthreads();

        // --- reduce + epilogue: each thread handles 4 outputs (b=eb, j=ej..+3)
        {
            float4v z0 = *(const float4v*)&zbuf[emt][0][em][en4];
            float4v z1 = *(const float4v*)&zbuf[emt][1][em][en4];
            float4v z2 = *(const float4v*)&zbuf[emt][2][em][en4];
            float4v z3 = *(const float4v*)&zbuf[emt][3][em][en4];
            size_t oidx = (size_t)t * (BATCH * HDIM) + (size_t)eb * HDIM + ej;
            float4v xp = *(const float4v*)(out + oidx);
            short4v hp_hi = *(const short4v*)(hhi + (size_t)eb * HDIM + ej);
            short4v hp_lo = *(const short4v*)(hlo + (size_t)eb * HDIM + ej);
            float4v al = *(const float4v*)(alpha + ej);

            float4v res;
            short4v nhi, nlo;
#pragma unroll
            for (int c = 0; c < 4; c++) {
                float z  = z0[c] + z1[c] + z2[c] + z3[c] + xp[c];
                float ht = tanhf(z);
                float hp = bf2f(hp_hi[c]) + bf2f(hp_lo[c]);
                float a  = al[c];
                float hn = (1.0f - a) * hp + a * ht;
                res[c] = hn;
                short hi = f2bf(hn);
                nhi[c] = hi;
                nlo[c] = f2bf(hn - bf2f(hi));
            }
            *(float4v*)(out + oidx) = res;   // overwrite xp with h_t
            if (t == SEQ - 1) {
                *(float4v*)(out + (size_t)SEQ * BATCH * HDIM + (size_t)eb * HDIM + ej) = res;
            }
            short* dhi = hbuf + (size_t)(nxt * 2 + 0) * BATCH * HDIM + (size_t)eb * HDIM + ej;
            short* dlo = hbuf + (size_t)(nxt * 2 + 1) * BATCH * HDIM + (size_t)eb * HDIM + ej;
            *(short4v*)dhi = nhi;
            *(short4v*)dlo = nlo;
        }
        grid.sync();
    }
}

// ---------------------------------------------------------------------------
extern "C" void kernel_launch(void* const* d_in, const int* in_sizes, int n_in,
                              void* d_out, int out_size, void* d_ws, size_t ws_size,
                              hipStream_t stream) {
    const float* x     = (const float*)d_in[0];
    const float* W_in  = (const float*)d_in[1];
    const float* W_hh  = (const float*)d_in[2];
    const float* bias  = (const float*)d_in[3];
    const float* alpha = (const float*)d_in[4];
    float* out = (float*)d_out;

    short* w_hi = (short*)d_ws;                           // 1024*1024 shorts (2 MB)
    short* w_lo = w_hi + (size_t)HDIM * HDIM;             // 2 MB
    short* hbuf = w_lo + (size_t)HDIM * HDIM;             // 2*2*64*1024 shorts (512 KB)

    prep_kernel<<<512, 256, 0, stream>>>(W_hh, w_hi, w_lo, hbuf);

    dim3 xg(SEQ * BATCH / XBM, HDIM / XBN);
    xproj_kernel<<<xg, 256, 0, stream>>>(x, W_in, bias, out);

    void* args[] = { (void*)&alpha, (void*)&w_hi, (void*)&w_lo, (void*)&hbuf, (void*)&out };
    (void)hipLaunchCooperativeKernel((const void*)rnn_kernel, dim3(32), dim3(512),
                                     args, 0, stream);
}

// Round 2
// 2762.714 us; speedup vs baseline: 2.8220x; 2.8220x over previous
//
#include <hip/hip_runtime.h>
#include <hip/hip_cooperative_groups.h>
#include <cstdint>
#include <cstddef>

#define SEQ   512
#define BATCH 64
#define DIN   256
#define HDIM  1024
#define NGROUP 8      // batch groups
#define GROWS  8      // rows per group
#define NSLAB  32     // column slabs (blocks per group)

typedef __attribute__((ext_vector_type(8)))  short  short8;
typedef __attribute__((ext_vector_type(4)))  float  float4v;
typedef __attribute__((ext_vector_type(2)))  float  float2v;

__device__ __forceinline__ short f2bf(float f) {
    union { float f; uint32_t u; } v; v.f = f;
    uint32_t u = v.u;
    uint32_t r = (u + 0x7fffu + ((u >> 16) & 1u)) >> 16;
    return (short)(r & 0xffffu);
}
__device__ __forceinline__ float bf2f(short s) {
    union { uint32_t u; float f; } v; v.u = ((uint32_t)(uint16_t)s) << 16;
    return v.f;
}

// ---------------------------------------------------------------------------
// prep: W_hh -> bf16 hi/lo planes; zero h buffer 0 (both planes); zero prog
// ---------------------------------------------------------------------------
__global__ void prep_kernel(const float* __restrict__ W_hh,
                            short* __restrict__ w_hi,
                            short* __restrict__ w_lo,
                            short* __restrict__ hbuf,
                            unsigned int* __restrict__ prog) {
    int tid = blockIdx.x * blockDim.x + threadIdx.x;
    int stride = gridDim.x * blockDim.x;
    for (int i = tid; i < HDIM * HDIM; i += stride) {
        float w = W_hh[i];
        short hi = f2bf(w);
        float lo = w - bf2f(hi);
        w_hi[i] = hi;
        w_lo[i] = f2bf(lo);
    }
    // zero buffer 0 (planes 0 and 1): first 2*BATCH*HDIM shorts
    for (int i = tid; i < 2 * BATCH * HDIM; i += stride) hbuf[i] = 0;
    for (int i = tid; i < NGROUP * NSLAB; i += stride) prog[i] = 0u;
}

// ---------------------------------------------------------------------------
// xproj: out[r][j] = sum_i X[r][i] * Win[j][i] + bias[j]   (unchanged R1)
// ---------------------------------------------------------------------------
#define XBM 128
#define XBN 128
#define XBK 32

__global__ __launch_bounds__(256) void xproj_kernel(
    const float* __restrict__ X,
    const float* __restrict__ Win,
    const float* __restrict__ bias,
    float* __restrict__ out)
{
    __shared__ float As[XBK][XBM + 4];
    __shared__ float Bs[XBK][XBN + 4];
    const int bm = blockIdx.x;
    const int bn = blockIdx.y;
    const int r0 = bm * XBM, c0 = bn * XBN;
    const int tid = threadIdx.x;
    const int tx = tid & 15, ty = tid >> 4;

    float acc[8][8];
#pragma unroll
    for (int i = 0; i < 8; i++)
#pragma unroll
        for (int j = 0; j < 8; j++) acc[i][j] = 0.f;

    for (int k0 = 0; k0 < DIN; k0 += XBK) {
#pragma unroll
        for (int r = 0; r < 4; r++) {
            int row = (tid >> 3) + 32 * r;
            int kk  = (tid & 7) * 4;
            float4v v = *(const float4v*)(X + (size_t)(r0 + row) * DIN + k0 + kk);
            As[kk + 0][row] = v[0]; As[kk + 1][row] = v[1];
            As[kk + 2][row] = v[2]; As[kk + 3][row] = v[3];
        }
#pragma unroll
        for (int r = 0; r < 4; r++) {
            int row = (tid >> 3) + 32 * r;
            int kk  = (tid & 7) * 4;
            float4v v = *(const float4v*)(Win + (size_t)(c0 + row) * DIN + k0 + kk);
            Bs[kk + 0][row] = v[0]; Bs[kk + 1][row] = v[1];
            Bs[kk + 2][row] = v[2]; Bs[kk + 3][row] = v[3];
        }
        __syncthreads();
#pragma unroll
        for (int k = 0; k < XBK; k++) {
            float4v a0 = *(const float4v*)&As[k][ty * 8];
            float4v a1 = *(const float4v*)&As[k][ty * 8 + 4];
            float4v b0 = *(const float4v*)&Bs[k][tx * 8];
            float4v b1 = *(const float4v*)&Bs[k][tx * 8 + 4];
            float a[8] = {a0[0],a0[1],a0[2],a0[3],a1[0],a1[1],a1[2],a1[3]};
            float b[8] = {b0[0],b0[1],b0[2],b0[3],b1[0],b1[1],b1[2],b1[3]};
#pragma unroll
            for (int i = 0; i < 8; i++)
#pragma unroll
                for (int j = 0; j < 8; j++) acc[i][j] += a[i] * b[j];
        }
        __syncthreads();
    }

    float4v ba = *(const float4v*)(bias + c0 + tx * 8);
    float4v bb = *(const float4v*)(bias + c0 + tx * 8 + 4);
#pragma unroll
    for (int i = 0; i < 8; i++) {
        size_t row = (size_t)(r0 + ty * 8 + i);
        float4v v0, v1;
#pragma unroll
        for (int j = 0; j < 4; j++) { v0[j] = acc[i][j] + ba[j]; v1[j] = acc[i][4 + j] + bb[j]; }
        *(float4v*)(out + row * HDIM + c0 + tx * 8)     = v0;
        *(float4v*)(out + row * HDIM + c0 + tx * 8 + 4) = v1;
    }
}

// ---------------------------------------------------------------------------
// rnn2: 256 blocks x 512 threads. Block (g,j): batch group g (8 rows),
// column slab j (32 cols). 8 waves = 8 K-slices of 128; each wave does both
// 16-col n-tiles (shared A-frags). W slab in registers (64 VGPR/thread).
// h exchange: relaxed agent-scope atomics (L2-bypass -> L3-coherent).
// Per-group flag barrier: monotonic prog[blk], 32-lane spin. No grid.sync.
// h_prev (blend path) kept fp32 in epilogue-thread registers.
// ---------------------------------------------------------------------------
__global__ __launch_bounds__(512, 2) void rnn2_kernel(
    const float* __restrict__ alpha,
    const short* __restrict__ w_hi,
    const short* __restrict__ w_lo,
    short* __restrict__ hbuf,          // [2 buf][2 plane][BATCH rows][HDIM]
    unsigned int* __restrict__ prog,   // [NGROUP*NSLAB]
    float* __restrict__ out)           // [SEQ][BATCH][HDIM] then h_n [BATCH][HDIM]
{
    __shared__ float zbuf[8][2][16][16];   // [kq][nt][m][n]

    const int blk  = blockIdx.x;
    const int g    = blk >> 5;          // batch group 0..7
    const int j    = blk & 31;          // slab 0..31
    const int tid  = threadIdx.x;
    const int wave = tid >> 6;          // kq 0..7
    const int lane = tid & 63;
    const int kq   = wave;
    const int ln15 = lane & 15;         // A row m / B col n within tile
    const int kg   = lane >> 4;         // 0..3 (8 k-elems each)
    const int k_base = kq * 128 + kg * 8;
    const bool mvalid = (ln15 < GROWS); // only 8 valid batch rows

    // --- W fragments, resident across all steps: [nt][kt][plane] ---
    short8 wf[2][4][2];
#pragma unroll
    for (int nt = 0; nt < 2; nt++)
#pragma unroll
        for (int kt = 0; kt < 4; kt++) {
            int col = j * 32 + nt * 16 + ln15;
            int k   = k_base + kt * 32;
            wf[nt][kt][0] = *(const short8*)(w_hi + (size_t)col * HDIM + k);
            wf[nt][kt][1] = *(const short8*)(w_lo + (size_t)col * HDIM + k);
        }

    // epilogue mapping: tid<128 -> (em 0..7, col pair cp)
    const int em = tid >> 4;
    const int cp = (tid & 15) * 2;
    const int erow = g * GROWS + em;
    const int egc  = j * 32 + cp;
    float hp0 = 0.f, hp1 = 0.f;
    float2v al = {0.f, 0.f};
    if (tid < 128) al = *(const float2v*)(alpha + egc);

    const int arow = g * GROWS + ln15;  // A-frag global batch row (if valid)

    for (int t = 0; t < SEQ; t++) {
        const int cur = t & 1, nxt = cur ^ 1;

        // --- MFMA phase over this wave's K-slice ---
        float4v acc0 = {0.f,0.f,0.f,0.f}, acc1 = {0.f,0.f,0.f,0.f};
#pragma unroll
        for (int kt = 0; kt < 4; kt++) {
            short8 ahi = (short8)0, alo = (short8)0;
            if (mvalid) {
                const unsigned long long* phi = (const unsigned long long*)
                    (hbuf + ((size_t)(cur*2+0)*BATCH + arow)*HDIM + k_base + kt*32);
                const unsigned long long* plo = (const unsigned long long*)
                    (hbuf + ((size_t)(cur*2+1)*BATCH + arow)*HDIM + k_base + kt*32);
                union { unsigned long long u[2]; short8 s; } uh, ul;
                uh.u[0] = __hip_atomic_load(phi,   __ATOMIC_RELAXED, __HIP_MEMORY_SCOPE_AGENT);
                uh.u[1] = __hip_atomic_load(phi+1, __ATOMIC_RELAXED, __HIP_MEMORY_SCOPE_AGENT);
                ul.u[0] = __hip_atomic_load(plo,   __ATOMIC_RELAXED, __HIP_MEMORY_SCOPE_AGENT);
                ul.u[1] = __hip_atomic_load(plo+1, __ATOMIC_RELAXED, __HIP_MEMORY_SCOPE_AGENT);
                ahi = uh.s; alo = ul.s;
            }
            acc0 = __builtin_amdgcn_mfma_f32_16x16x32_bf16(ahi, wf[0][kt][0], acc0, 0, 0, 0);
            acc0 = __builtin_amdgcn_mfma_f32_16x16x32_bf16(ahi, wf[0][kt][1], acc0, 0, 0, 0);
            acc0 = __builtin_amdgcn_mfma_f32_16x16x32_bf16(alo, wf[0][kt][0], acc0, 0, 0, 0);
            acc1 = __builtin_amdgcn_mfma_f32_16x16x32_bf16(ahi, wf[1][kt][0], acc1, 0, 0, 0);
            acc1 = __builtin_amdgcn_mfma_f32_16x16x32_bf16(ahi, wf[1][kt][1], acc1, 0, 0, 0);
            acc1 = __builtin_amdgcn_mfma_f32_16x16x32_bf16(alo, wf[1][kt][0], acc1, 0, 0, 0);
        }
        // C/D layout: col = lane&15, row = (lane>>4)*4 + reg
#pragma unroll
        for (int reg = 0; reg < 4; reg++) {
            int m = kg * 4 + reg;
            zbuf[kq][0][m][ln15] = acc0[reg];
            zbuf[kq][1][m][ln15] = acc1[reg];
        }
        __syncthreads();

        // --- reduce + epilogue: 128 threads, one (row, col-pair) each ---
        if (tid < 128) {
            float z0 = 0.f, z1 = 0.f;
            const int nt0 = cp >> 4, n0 = cp & 15;
#pragma unroll
            for (int q = 0; q < 8; q++) {
                z0 += zbuf[q][nt0][em][n0];
                z1 += zbuf[q][nt0][em][n0 + 1];
            }
            size_t oidx = (size_t)t * (BATCH * HDIM) + (size_t)erow * HDIM + egc;
            float2v xp = *(const float2v*)(out + oidx);
            float ht0 = tanhf(z0 + xp[0]);
            float ht1 = tanhf(z1 + xp[1]);
            hp0 = (1.0f - al[0]) * hp0 + al[0] * ht0;
            hp1 = (1.0f - al[1]) * hp1 + al[1] * ht1;
            float2v res = {hp0, hp1};
            *(float2v*)(out + oidx) = res;
            if (t == SEQ - 1) {
                *(float2v*)(out + (size_t)SEQ * BATCH * HDIM + (size_t)erow * HDIM + egc) = res;
            }
            short h0 = f2bf(hp0), h1 = f2bf(hp1);
            short l0 = f2bf(hp0 - bf2f(h0)), l1 = f2bf(hp1 - bf2f(h1));
            uint32_t packh = (uint32_t)(uint16_t)h0 | ((uint32_t)(uint16_t)h1 << 16);
            uint32_t packl = (uint32_t)(uint16_t)l0 | ((uint32_t)(uint16_t)l1 << 16);
            uint32_t* dhi = (uint32_t*)(hbuf + ((size_t)(nxt*2+0)*BATCH + erow)*HDIM + egc);
            uint32_t* dlo = (uint32_t*)(hbuf + ((size_t)(nxt*2+1)*BATCH + erow)*HDIM + egc);
            __hip_atomic_store(dhi, packh, __ATOMIC_RELAXED, __HIP_MEMORY_SCOPE_AGENT);
            __hip_atomic_store(dlo, packl, __ATOMIC_RELAXED, __HIP_MEMORY_SCOPE_AGENT);
        }

        if (t < SEQ - 1) {
            // drain this wave's stores to the device coherence point, then
            // block-barrier so ALL waves' stores are complete before signaling
            __builtin_amdgcn_s_waitcnt(0);
            __syncthreads();
            if (tid == 0) {
                __hip_atomic_store(&prog[blk], (unsigned int)(t + 1),
                                   __ATOMIC_RELAXED, __HIP_MEMORY_SCOPE_AGENT);
            }
            if (tid < NSLAB) {
                while (__hip_atomic_load(&prog[g * NSLAB + tid],
                                         __ATOMIC_RELAXED, __HIP_MEMORY_SCOPE_AGENT)
                       < (unsigned int)(t + 1)) {
                    __builtin_amdgcn_s_sleep(1);
                }
            }
            __syncthreads();
        }
    }
}

// ---------------------------------------------------------------------------
extern "C" void kernel_launch(void* const* d_in, const int* in_sizes, int n_in,
                              void* d_out, int out_size, void* d_ws, size_t ws_size,
                              hipStream_t stream) {
    const float* x     = (const float*)d_in[0];
    const float* W_in  = (const float*)d_in[1];
    const float* W_hh  = (const float*)d_in[2];
    const float* bias  = (const float*)d_in[3];
    const float* alpha = (const float*)d_in[4];
    float* out = (float*)d_out;

    short* w_hi = (short*)d_ws;                               // 2 MB
    short* w_lo = w_hi + (size_t)HDIM * HDIM;                 // 2 MB
    short* hbuf = w_lo + (size_t)HDIM * HDIM;                 // 512 KB
    unsigned int* prog = (unsigned int*)(hbuf + (size_t)2 * 2 * BATCH * HDIM);

    prep_kernel<<<512, 256, 0, stream>>>(W_hh, w_hi, w_lo, hbuf, prog);

    dim3 xg(SEQ * BATCH / XBM, HDIM / XBN);
    xproj_kernel<<<xg, 256, 0, stream>>>(x, W_in, bias, out);

    void* args[] = { (void*)&alpha, (void*)&w_hi, (void*)&w_lo,
                     (void*)&hbuf, (void*)&prog, (void*)&out };
    (void)hipLaunchCooperativeKernel((const void*)rnn2_kernel,
                                     dim3(NGROUP * NSLAB), dim3(512),
                                     args, 0, stream);
}